// Round 14
// baseline (1458.688 us; speedup 1.0000x reference)
//
#include <hip/hip_runtime.h>

typedef unsigned int u32;
typedef unsigned short u16;
typedef __bf16 bf16x8 __attribute__((ext_vector_type(8)));
typedef float f32x4 __attribute__((ext_vector_type(4)));
typedef u32 u32x4 __attribute__((ext_vector_type(4)));
typedef u32 u32x2 __attribute__((ext_vector_type(2)));

#define NTOK 64
#define CDIM 256
#define NH 8
#define WPB 8          // windows per persistent block (4096 / 512)

// ---- workspace layout (u16 units) ----
#define WS_HDR 8
#define BIAS_O (WS_HDR)             // [8][n 64][m 64] expanded bias (32768)
#define WQKV_O (BIAS_O + 32768)     // w_qkv bf16                    (196608)
#define BQKV_O (WQKV_O + 196608)    // b_qkv bf16                    (768)
#define WPRJ_O (BQKV_O + 768)       // w_proj bf16                   (65536)
#define BPRJ_O (WPRJ_O + 65536)     // b_proj bf16                   (256)

// ---- LDS: double-buffered x/y tile, 2 x [64][520B] = 66,560 B (2 blocks/CU) ----
#define XROW 520
#define BUFB 33280
#define LDS_BYTES (2 * BUFB)

__device__ __forceinline__ float bf2f(u16 u) {
  union { u32 i; float f; } z; z.i = ((u32)u) << 16; return z.f;
}
__device__ __forceinline__ u16 f2bf(float f) {
  __bf16 h = (__bf16)f; return __builtin_bit_cast(u16, h);
}
__device__ __forceinline__ u32 pk2(float a, float b) {
  return (u32)f2bf(a) | ((u32)f2bf(b) << 16);
}
__device__ __forceinline__ float fetchf(const void* p, int idx, int isbf) {
  return isbf ? bf2f(((const u16*)p)[idx]) : ((const float*)p)[idx];
}

// Universal acc->frag repack (HW-verified rounds 6-13).
__device__ __forceinline__ bf16x8 frag_from(u32 p00, u32 p01, u32 p10, u32 p11,
                                            int s0, int s1, bool hi) {
  u32 A0 = (u32)__shfl((int)p00, s0, 64);
  u32 A1 = (u32)__shfl((int)p01, s0, 64);
  u32 B0 = (u32)__shfl((int)p10, s0, 64);
  u32 B1 = (u32)__shfl((int)p11, s0, 64);
  u32 C0 = (u32)__shfl((int)p00, s1, 64);
  u32 C1 = (u32)__shfl((int)p01, s1, 64);
  u32 D0 = (u32)__shfl((int)p10, s1, 64);
  u32 D1 = (u32)__shfl((int)p11, s1, 64);
  u32x4 f;
  f[0] = hi ? B0 : A0;  f[1] = hi ? B1 : A1;
  f[2] = hi ? D0 : C0;  f[3] = hi ? D1 : C1;
  return __builtin_bit_cast(bf16x8, f);
}

__global__ void detect_dtype(const u16* __restrict__ x, int* __restrict__ flag) {
  __shared__ int cnt;
  if (threadIdx.x == 0) cnt = 0;
  __syncthreads();
  int sane = 0;
  for (int i = threadIdx.x; i < 2048; i += 256) {
    u16 u = x[2 * i];
    int e = (u >> 7) & 0xFF;
    sane += (e == 0 || (e >= 90 && e <= 160)) ? 1 : 0;
  }
  atomicAdd(&cnt, sane);
  __syncthreads();
  if (threadIdx.x == 0) *flag = (cnt >= 1638) ? 1 : 0;
}

// bias expanded to [h][n][m]
__global__ void cvt_params(const void* __restrict__ wqkv, const void* __restrict__ bqkv,
                           const void* __restrict__ btab, const void* __restrict__ wprj,
                           const void* __restrict__ bprj, void* __restrict__ wsraw) {
  u16* ws = (u16*)wsraw;
  const int isbf = *(const int*)wsraw;
  int i = blockIdx.x * 256 + threadIdx.x;
  if (i < 32768) {
    int n = (i >> 6) & 63, m = i & 63, h = i >> 12;
    int r0 = (n >> 3) - (m >> 3) + 7, r1 = (n & 7) - (m & 7) + 7;
    ws[BIAS_O + i] = f2bf(fetchf(btab, (r0 * 15 + r1) * NH + h, isbf));
  } else if (i < 32768 + 196608) {
    int j = i - 32768;
    ws[WQKV_O + j] = f2bf(fetchf(wqkv, j, isbf));
  } else if (i < 32768 + 196608 + 768) {
    int j = i - (32768 + 196608);
    ws[BQKV_O + j] = f2bf(fetchf(bqkv, j, isbf));
  } else if (i < 32768 + 196608 + 768 + 65536) {
    int j = i - (32768 + 196608 + 768);
    ws[WPRJ_O + j] = f2bf(fetchf(wprj, j, isbf));
  } else if (i < 32768 + 196608 + 768 + 65536 + 256) {
    int j = i - (32768 + 196608 + 768 + 65536);
    ws[BPRJ_O + j] = f2bf(fetchf(bprj, j, isbf));
  }
}

// Transposed qkv ch-tile (reads x from XB): acc rows = channels, cols = tokens.
#define TILE_T(PK, CHT, CHB, SCL) {                                                   \
    bf16x8 wf[8];                                                                     \
    const u16* wrow = ws + WQKV_O + ((CHB) + c) * CDIM;                               \
    _Pragma("unroll")                                                                 \
    for (int ks = 0; ks < 8; ++ks) wf[ks] = *(const bf16x8*)(wrow + ks * 32 + g * 8); \
    f32x4 binit;                                                                      \
    { u32x2 bp = *(const u32x2*)(ws + BQKV_O + (CHB) + 4 * g);                        \
      binit[0] = bf2f((u16)(bp[0] & 0xffff)); binit[1] = bf2f((u16)(bp[0] >> 16));    \
      binit[2] = bf2f((u16)(bp[1] & 0xffff)); binit[3] = bf2f((u16)(bp[1] >> 16)); }  \
    _Pragma("unroll")                                                                 \
    for (int nt = 0; nt < 4; ++nt) {                                                  \
      f32x4 acc = binit;                                                              \
      _Pragma("unroll")                                                               \
      for (int ks = 0; ks < 8; ++ks) {                                                \
        bf16x8 xf = *(const bf16x8*)(XB + (16 * nt + c) * XROW + ks * 64 + g * 16);   \
        acc = __builtin_amdgcn_mfma_f32_16x16x32_bf16(wf[ks], xf, acc, 0, 0, 0);      \
      }                                                                               \
      PK[CHT][nt][0] = pk2(acc[0] * (SCL), acc[1] * (SCL));                           \
      PK[CHT][nt][1] = pk2(acc[2] * (SCL), acc[3] * (SCL));                           \
    } }

// Normal qkv ch-tile (v): acc rows = tokens, col = channel.
#define TILE_N(PK, CHT, CHB) {                                                        \
    bf16x8 wf[8];                                                                     \
    const u16* wrow = ws + WQKV_O + ((CHB) + c) * CDIM;                               \
    _Pragma("unroll")                                                                 \
    for (int ks = 0; ks < 8; ++ks) wf[ks] = *(const bf16x8*)(wrow + ks * 32 + g * 8); \
    const float badd = bf2f(ws[BQKV_O + (CHB) + c]);                                  \
    _Pragma("unroll")                                                                 \
    for (int nt = 0; nt < 4; ++nt) {                                                  \
      f32x4 acc = {badd, badd, badd, badd};                                           \
      _Pragma("unroll")                                                               \
      for (int ks = 0; ks < 8; ++ks) {                                                \
        bf16x8 xf = *(const bf16x8*)(XB + (16 * nt + c) * XROW + ks * 64 + g * 16);   \
        acc = __builtin_amdgcn_mfma_f32_16x16x32_bf16(xf, wf[ks], acc, 0, 0, 0);      \
      }                                                                               \
      PK[CHT][nt][0] = pk2(acc[0], acc[1]);                                           \
      PK[CHT][nt][1] = pk2(acc[2], acc[3]);                                           \
    } }

// issue next-window x loads into prefetch regs (in flight across the window)
#define ISSUE_X(BW) {                                                                 \
    if (isbf) {                                                                       \
      const u32x4* gx = (const u32x4*)((const u16*)xraw + (size_t)(BW) * (NTOK*CDIM));\
      _Pragma("unroll")                                                               \
      for (int j = 0; j < 4; ++j) xpru[j] = gx[tid + j * 512];                        \
    } else {                                                                          \
      const f32x4* gx = (const f32x4*)((const float*)xraw + (size_t)(BW) * (NTOK*CDIM));\
      _Pragma("unroll")                                                               \
      for (int j = 0; j < 8; ++j) xpr[j] = gx[tid + j * 512];                         \
    } }

// write prefetch regs -> LDS buffer PB (compiler inserts vmcnt wait on use)
#define WRITE_X(PB) {                                                                 \
    if (isbf) {                                                                       \
      _Pragma("unroll")                                                               \
      for (int j = 0; j < 4; ++j) {                                                   \
        int q = tid + j * 512, row = q >> 5, c8 = q & 31;                             \
        *(u32x4*)((PB) + row * XROW + c8 * 16) = xpru[j];                             \
      }                                                                               \
    } else {                                                                          \
      _Pragma("unroll")                                                               \
      for (int j = 0; j < 8; ++j) {                                                   \
        int q = tid + j * 512, row = q >> 6, c4 = q & 63;                             \
        u32x2 pkv;                                                                    \
        pkv[0] = pk2(xpr[j][0], xpr[j][1]);                                           \
        pkv[1] = pk2(xpr[j][2], xpr[j][3]);                                           \
        *(u32x2*)((PB) + row * XROW + c4 * 8) = pkv;                                  \
      }                                                                               \
    } }

// Persistent: 512 blocks = exactly 2 resident/CU; each runs WPB windows with
// x double-buffering. Cap (512,2)=256 unified: r8-proven spill-free regime
// (VGPR 108 + ~64 acc; prefetch adds ~32 transient -> still far under cap).
__global__ __launch_bounds__(512, 2)
void win_attn_persist(const void* __restrict__ xraw, const void* __restrict__ wsraw,
                      float* __restrict__ out)
{
  __shared__ __align__(16) unsigned char lds[LDS_BYTES];
  const u16* ws  = (const u16*)wsraw;
  const int isbf = *(const int*)wsraw;
  const int tid  = threadIdx.x;
  const int w    = tid >> 6;     // wave id = head id
  const int lane = tid & 63;
  const int c    = lane & 15;
  const int g    = lane >> 4;
  const float scale = 0.1767766952966369f;  // 32^-0.5
  const int b0   = blockIdx.x * WPB;

  const int s0 = c + 32 * (g & 1), s1 = s0 + 16;
  const bool hi = ((g >> 1) & 1) != 0;

  f32x4 xpr[8];    // f32-path prefetch regs (32 VGPR)
  u32x4 xpru[4];   // bf16-path prefetch regs

  // ---- preamble: x[b0] -> buf0 directly; issue x[b0+1]
  ISSUE_X(b0);
  WRITE_X(lds);
  ISSUE_X(b0 + 1);

  for (int i = 0; i < WPB; ++i) {
    unsigned char* XB = lds + (i & 1) * BUFB;          // current x / y buffer
    unsigned char* XN = lds + ((i + 1) & 1) * BUFB;    // next x buffer
    const int b = b0 + i;

    __syncthreads();   // B1: x_i staged; prior proj (reader of XN) complete
    if (i < WPB - 1) WRITE_X(XN);   // land x_{i+1} (waits vmcnt internally)

    // ---- stage 1: per-head q,k (transposed) and v (normal), packed in regs
    u32 qpk[2][4][2], kpk[2][4][2];
    bf16x8 bvf[2][2];
    TILE_T(qpk, 0, 32 * w,            scale);
    TILE_T(qpk, 1, 32 * w + 16,       scale);
    TILE_T(kpk, 0, 256 + 32 * w,      1.0f);
    TILE_T(kpk, 1, 256 + 32 * w + 16, 1.0f);
    {
      u32 vpk[2][4][2];
      TILE_N(vpk, 0, 512 + 32 * w);
      TILE_N(vpk, 1, 512 + 32 * w + 16);
#pragma unroll
      for (int dt = 0; dt < 2; ++dt)
#pragma unroll
        for (int k2 = 0; k2 < 2; ++k2)
          bvf[dt][k2] = frag_from(vpk[dt][2 * k2][0], vpk[dt][2 * k2][1],
                                  vpk[dt][2 * k2 + 1][0], vpk[dt][2 * k2 + 1][1], s0, s1, hi);
    }
    __syncthreads();   // B2: x_i dead -> y_i may overlay XB
    if (i < WPB - 2) ISSUE_X(b0 + i + 2);   // prefetch regs free again

    // ---- k -> A-frags
    bf16x8 bkf[4];
#pragma unroll
    for (int mt = 0; mt < 4; ++mt)
      bkf[mt] = frag_from(kpk[0][mt][0], kpk[0][mt][1], kpk[1][mt][0], kpk[1][mt][1], s0, s1, hi);

    // ---- S^T + softmax + P pack (r8-verified)
    u32 Ppk[4][4][2];
#pragma unroll
    for (int nt = 0; nt < 4; ++nt) {
      bf16x8 aqf = frag_from(qpk[0][nt][0], qpk[0][nt][1], qpk[1][nt][0], qpk[1][nt][1], s0, s1, hi);
      f32x4 st[4];
#pragma unroll
      for (int mt = 0; mt < 4; ++mt) {
        u32x2 bp = *(const u32x2*)(ws + BIAS_O + (w << 12) + ((16 * nt + c) << 6) + 16 * mt + 4 * g);
        st[mt][0] = bf2f((u16)(bp[0] & 0xffff)); st[mt][1] = bf2f((u16)(bp[0] >> 16));
        st[mt][2] = bf2f((u16)(bp[1] & 0xffff)); st[mt][3] = bf2f((u16)(bp[1] >> 16));
      }
#pragma unroll
      for (int mt = 0; mt < 4; ++mt)
        st[mt] = __builtin_amdgcn_mfma_f32_16x16x32_bf16(bkf[mt], aqf, st[mt], 0, 0, 0);
      float mx = st[0][0];
#pragma unroll
      for (int mt = 0; mt < 4; ++mt)
#pragma unroll
        for (int r = 0; r < 4; ++r) mx = fmaxf(mx, st[mt][r]);
      mx = fmaxf(mx, __shfl_xor(mx, 16));
      mx = fmaxf(mx, __shfl_xor(mx, 32));
      float sum = 0.f;
#pragma unroll
      for (int mt = 0; mt < 4; ++mt)
#pragma unroll
        for (int r = 0; r < 4; ++r) { float e = __expf(st[mt][r] - mx); st[mt][r] = e; sum += e; }
      sum += __shfl_xor(sum, 16);
      sum += __shfl_xor(sum, 32);
      float inv = 1.0f / sum;
#pragma unroll
      for (int mt = 0; mt < 4; ++mt) {
        Ppk[mt][nt][0] = pk2(st[mt][0] * inv, st[mt][1] * inv);
        Ppk[mt][nt][1] = pk2(st[mt][2] * inv, st[mt][3] * inv);
      }
    }

    // ---- PV; paf per-k2 transient
    f32x4 o[4][2] = {{{0,0,0,0},{0,0,0,0}},{{0,0,0,0},{0,0,0,0}},
                     {{0,0,0,0},{0,0,0,0}},{{0,0,0,0},{0,0,0,0}}};
#pragma unroll
    for (int k2 = 0; k2 < 2; ++k2) {
      bf16x8 paf4[4];
#pragma unroll
      for (int nt = 0; nt < 4; ++nt)
        paf4[nt] = frag_from(Ppk[2 * k2][nt][0], Ppk[2 * k2][nt][1],
                             Ppk[2 * k2 + 1][nt][0], Ppk[2 * k2 + 1][nt][1], s0, s1, hi);
#pragma unroll
      for (int nt = 0; nt < 4; ++nt) {
        o[nt][0] = __builtin_amdgcn_mfma_f32_16x16x32_bf16(paf4[nt], bvf[0][k2], o[nt][0], 0, 0, 0);
        o[nt][1] = __builtin_amdgcn_mfma_f32_16x16x32_bf16(paf4[nt], bvf[1][k2], o[nt][1], 0, 0, 0);
      }
    }

    // ---- y -> XB (disjoint per-wave cols)
#pragma unroll
    for (int nt = 0; nt < 4; ++nt)
#pragma unroll
      for (int dt = 0; dt < 2; ++dt)
#pragma unroll
        for (int r = 0; r < 4; ++r) {
          int n = 16 * nt + 4 * g + r, col = 32 * w + 16 * dt + c;
          *(u16*)(XB + n * XROW + col * 2) = f2bf(o[nt][dt][r]);
        }
    __syncthreads();   // B3: y complete

    // ---- proj -> out[b]
    float* gout = out + (size_t)b * (NTOK * CDIM);
#pragma unroll
    for (int ct = 0; ct < 2; ++ct) {
      const int colw = 32 * w + 16 * ct + c;
      const float badd = bf2f(ws[BPRJ_O + colw]);
      f32x4 acc[4];
#pragma unroll
      for (int rt = 0; rt < 4; ++rt)
#pragma unroll
        for (int r = 0; r < 4; ++r) acc[rt][r] = badd;
      const u16* wrow = ws + WPRJ_O + colw * CDIM;
#pragma unroll
      for (int ks = 0; ks < 8; ++ks) {
        bf16x8 wf = *(const bf16x8*)(wrow + ks * 32 + g * 8);
#pragma unroll
        for (int rt = 0; rt < 4; ++rt) {
          bf16x8 ay = *(const bf16x8*)(XB + (16 * rt + c) * XROW + ks * 64 + g * 16);
          acc[rt] = __builtin_amdgcn_mfma_f32_16x16x32_bf16(ay, wf, acc[rt], 0, 0, 0);
        }
      }
#pragma unroll
      for (int rt = 0; rt < 4; ++rt)
#pragma unroll
        for (int r = 0; r < 4; ++r) {
          int n = 16 * rt + 4 * g + r;
          gout[n * CDIM + colw] = acc[rt][r];
        }
    }
  }
}

extern "C" void kernel_launch(void* const* d_in, const int* in_sizes, int n_in,
                              void* d_out, int out_size, void* d_ws, size_t ws_size,
                              hipStream_t stream) {
  (void)in_sizes; (void)n_in; (void)out_size; (void)ws_size;
  detect_dtype<<<dim3(1), dim3(256), 0, stream>>>((const u16*)d_in[0], (int*)d_ws);
  cvt_params<<<dim3(1156), dim3(256), 0, stream>>>(d_in[1], d_in[2], d_in[3], d_in[4],
                                                   d_in[5], d_ws);
  win_attn_persist<<<dim3(512), dim3(512), 0, stream>>>(d_in[0], d_ws, (float*)d_out);
}

// Round 15
// 467.438 us; speedup vs baseline: 3.1206x; 3.1206x over previous
//
#include <hip/hip_runtime.h>

typedef unsigned int u32;
typedef unsigned short u16;
typedef __bf16 bf16x8 __attribute__((ext_vector_type(8)));
typedef short short4_ __attribute__((ext_vector_type(4)));
typedef float f32x4 __attribute__((ext_vector_type(4)));
typedef u32 u32x4 __attribute__((ext_vector_type(4)));
typedef u32 u32x2 __attribute__((ext_vector_type(2)));

#if __has_builtin(__builtin_amdgcn_mfma_f32_16x16x16bf16_1k)
#define HAVE_MFMA16 1
#else
#define HAVE_MFMA16 0
#endif

#define NTOK 64
#define CDIM 256
#define NH 8

// ---- workspace layout (u16 units) ----
#define WS_HDR 8
#define BIAS_O (WS_HDR)             // [8][n 64][m 64] expanded bias (32768)
#define WQKV_O (BIAS_O + 32768)     // w_qkv bf16                    (196608)
#define BQKV_O (WQKV_O + 196608)    // b_qkv bf16                    (768)
#define WPRJ_O (BQKV_O + 768)       // w_proj bf16                   (65536)
#define BPRJ_O (WPRJ_O + 65536)     // b_proj bf16                   (256)

// ---- LDS: x tile [64][520B] = 33,280 B; reused as y tile after B2 ----
#define XROW 520
#define LDS_BYTES 33280

__device__ __forceinline__ float bf2f(u16 u) {
  union { u32 i; float f; } z; z.i = ((u32)u) << 16; return z.f;
}
__device__ __forceinline__ u16 f2bf(float f) {
  __bf16 h = (__bf16)f; return __builtin_bit_cast(u16, h);
}
__device__ __forceinline__ u32 pk2(float a, float b) {
  return (u32)f2bf(a) | ((u32)f2bf(b) << 16);
}
__device__ __forceinline__ float fetchf(const void* p, int idx, int isbf) {
  return isbf ? bf2f(((const u16*)p)[idx]) : ((const float*)p)[idx];
}
// two packed u32 (4 bf16, reg-order j=0..3) -> K=16 MFMA operand
__device__ __forceinline__ short4_ op16(u32 lo, u32 hi) {
  u32x2 z; z[0] = lo; z[1] = hi;
  return __builtin_bit_cast(short4_, z);
}

// Universal acc->frag repack (HW-verified rounds 6-14; fallback path only).
__device__ __forceinline__ bf16x8 frag_from(u32 p00, u32 p01, u32 p10, u32 p11,
                                            int s0, int s1, bool hi) {
  u32 A0 = (u32)__shfl((int)p00, s0, 64);
  u32 A1 = (u32)__shfl((int)p01, s0, 64);
  u32 B0 = (u32)__shfl((int)p10, s0, 64);
  u32 B1 = (u32)__shfl((int)p11, s0, 64);
  u32 C0 = (u32)__shfl((int)p00, s1, 64);
  u32 C1 = (u32)__shfl((int)p01, s1, 64);
  u32 D0 = (u32)__shfl((int)p10, s1, 64);
  u32 D1 = (u32)__shfl((int)p11, s1, 64);
  u32x4 f;
  f[0] = hi ? B0 : A0;  f[1] = hi ? B1 : A1;
  f[2] = hi ? D0 : C0;  f[3] = hi ? D1 : C1;
  return __builtin_bit_cast(bf16x8, f);
}

__global__ void detect_dtype(const u16* __restrict__ x, int* __restrict__ flag) {
  __shared__ int cnt;
  if (threadIdx.x == 0) cnt = 0;
  __syncthreads();
  int sane = 0;
  for (int i = threadIdx.x; i < 2048; i += 256) {
    u16 u = x[2 * i];
    int e = (u >> 7) & 0xFF;
    sane += (e == 0 || (e >= 90 && e <= 160)) ? 1 : 0;
  }
  atomicAdd(&cnt, sane);
  __syncthreads();
  if (threadIdx.x == 0) *flag = (cnt >= 1638) ? 1 : 0;
}

// bias expanded to [h][n][m]
__global__ void cvt_params(const void* __restrict__ wqkv, const void* __restrict__ bqkv,
                           const void* __restrict__ btab, const void* __restrict__ wprj,
                           const void* __restrict__ bprj, void* __restrict__ wsraw) {
  u16* ws = (u16*)wsraw;
  const int isbf = *(const int*)wsraw;
  int i = blockIdx.x * 256 + threadIdx.x;
  if (i < 32768) {
    int n = (i >> 6) & 63, m = i & 63, h = i >> 12;
    int r0 = (n >> 3) - (m >> 3) + 7, r1 = (n & 7) - (m & 7) + 7;
    ws[BIAS_O + i] = f2bf(fetchf(btab, (r0 * 15 + r1) * NH + h, isbf));
  } else if (i < 32768 + 196608) {
    int j = i - 32768;
    ws[WQKV_O + j] = f2bf(fetchf(wqkv, j, isbf));
  } else if (i < 32768 + 196608 + 768) {
    int j = i - (32768 + 196608);
    ws[BQKV_O + j] = f2bf(fetchf(bqkv, j, isbf));
  } else if (i < 32768 + 196608 + 768 + 65536) {
    int j = i - (32768 + 196608 + 768);
    ws[WPRJ_O + j] = f2bf(fetchf(wprj, j, isbf));
  } else if (i < 32768 + 196608 + 768 + 65536 + 256) {
    int j = i - (32768 + 196608 + 768 + 65536);
    ws[BPRJ_O + j] = f2bf(fetchf(bprj, j, isbf));
  }
}

// Transposed qkv ch-tile: acc value = qkv[tok=16nt+c][ch=CHB+4g+reg] (r8-verified).
#define TILE_T(PK, CHT, CHB, SCL) {                                                   \
    bf16x8 wf[8];                                                                     \
    const u16* wrow = ws + WQKV_O + ((CHB) + c) * CDIM;                               \
    _Pragma("unroll")                                                                 \
    for (int ks = 0; ks < 8; ++ks) wf[ks] = *(const bf16x8*)(wrow + ks * 32 + g * 8); \
    f32x4 binit;                                                                      \
    { u32x2 bp = *(const u32x2*)(ws + BQKV_O + (CHB) + 4 * g);                        \
      binit[0] = bf2f((u16)(bp[0] & 0xffff)); binit[1] = bf2f((u16)(bp[0] >> 16));    \
      binit[2] = bf2f((u16)(bp[1] & 0xffff)); binit[3] = bf2f((u16)(bp[1] >> 16)); }  \
    _Pragma("unroll")                                                                 \
    for (int nt = 0; nt < 4; ++nt) {                                                  \
      f32x4 acc = binit;                                                              \
      _Pragma("unroll")                                                               \
      for (int ks = 0; ks < 8; ++ks) {                                                \
        bf16x8 xf = *(const bf16x8*)(lds + (16 * nt + c) * XROW + ks * 64 + g * 16);  \
        acc = __builtin_amdgcn_mfma_f32_16x16x32_bf16(wf[ks], xf, acc, 0, 0, 0);      \
      }                                                                               \
      PK[CHT][nt][0] = pk2(acc[0] * (SCL), acc[1] * (SCL));                           \
      PK[CHT][nt][1] = pk2(acc[2] * (SCL), acc[3] * (SCL));                           \
    } }

// Normal qkv ch-tile (v): acc value = v[tok=16nt+4g+reg][ch=CHB+c].
#define TILE_N(PK, CHT, CHB) {                                                        \
    bf16x8 wf[8];                                                                     \
    const u16* wrow = ws + WQKV_O + ((CHB) + c) * CDIM;                               \
    _Pragma("unroll")                                                                 \
    for (int ks = 0; ks < 8; ++ks) wf[ks] = *(const bf16x8*)(wrow + ks * 32 + g * 8); \
    const float badd = bf2f(ws[BQKV_O + (CHB) + c]);                                  \
    _Pragma("unroll")                                                                 \
    for (int nt = 0; nt < 4; ++nt) {                                                  \
      f32x4 acc = {badd, badd, badd, badd};                                           \
      _Pragma("unroll")                                                               \
      for (int ks = 0; ks < 8; ++ks) {                                                \
        bf16x8 xf = *(const bf16x8*)(lds + (16 * nt + c) * XROW + ks * 64 + g * 16);  \
        acc = __builtin_amdgcn_mfma_f32_16x16x32_bf16(xf, wf[ks], acc, 0, 0, 0);      \
      }                                                                               \
      PK[CHT][nt][0] = pk2(acc[0], acc[1]);                                           \
      PK[CHT][nt][1] = pk2(acc[2], acc[3]);                                           \
    } }

// r8 shell: (512,2) cap 256 = the ONLY proven spill-free regime for this state.
__global__ __launch_bounds__(512, 2)
void win_attn_fused(const void* __restrict__ xraw, const void* __restrict__ wsraw,
                    float* __restrict__ out)
{
  __shared__ __align__(16) unsigned char lds[LDS_BYTES];
  const u16* ws  = (const u16*)wsraw;
  const int isbf = *(const int*)wsraw;
  const int b    = blockIdx.x;
  const int tid  = threadIdx.x;
  const int w    = tid >> 6;     // wave id = head id
  const int lane = tid & 63;
  const int c    = lane & 15;
  const int g    = lane >> 4;
  const float scale = 0.1767766952966369f;  // 32^-0.5

  // ---- stage 0: x[b] (64x256) -> LDS bf16 [64][520B]
  if (isbf) {
    const u32x4* gx = (const u32x4*)((const u16*)xraw + (size_t)b * (NTOK * CDIM));
#pragma unroll
    for (int i = 0; i < 4; ++i) {
      int q = tid + i * 512;
      int row = q >> 5, c8 = q & 31;
      *(u32x4*)(lds + row * XROW + c8 * 16) = gx[q];
    }
  } else {
    const f32x4* gx = (const f32x4*)((const float*)xraw + (size_t)b * (NTOK * CDIM));
#pragma unroll
    for (int i = 0; i < 8; ++i) {
      int q = tid + i * 512;
      int row = q >> 6, c4 = q & 63;
      f32x4 v = gx[q];
      u32x2 pkv;
      pkv[0] = pk2(v[0], v[1]);
      pkv[1] = pk2(v[2], v[3]);
      *(u32x2*)(lds + row * XROW + c4 * 8) = pkv;
    }
  }
  __syncthreads();   // B1

  const int s0 = c + 32 * (g & 1), s1 = s0 + 16;
  const bool hi = ((g >> 1) & 1) != 0;
  const int h = w;
  (void)s0; (void)s1; (void)hi;

  // ---- stage 1: per-head q,k (transposed) and v (normal), packed in registers
  u32 qpk[2][4][2], kpk[2][4][2], vpk[2][4][2];
  TILE_T(qpk, 0, 32 * w,            scale);
  TILE_T(qpk, 1, 32 * w + 16,       scale);
  TILE_T(kpk, 0, 256 + 32 * w,      1.0f);
  TILE_T(kpk, 1, 256 + 32 * w + 16, 1.0f);
  TILE_N(vpk, 0, 512 + 32 * w);
  TILE_N(vpk, 1, 512 + 32 * w + 16);

#if !HAVE_MFMA16
  // fallback (r8): v -> B-frags now (frees vpk)
  bf16x8 bvf[2][2];
#pragma unroll
  for (int dt = 0; dt < 2; ++dt)
#pragma unroll
    for (int k2 = 0; k2 < 2; ++k2)
      bvf[dt][k2] = frag_from(vpk[dt][2 * k2][0], vpk[dt][2 * k2][1],
                              vpk[dt][2 * k2 + 1][0], vpk[dt][2 * k2 + 1][1], s0, s1, hi);
#endif
  __syncthreads();   // B2: x-LDS dead; region holds y below

#if HAVE_MFMA16
  // ==== K=16 path: operands come DIRECTLY from packed accs (zero shuffles) ====
  // S^T[m=16mt+4g+reg][n=16nt+c] = sum_ch k[m][ch] q[n][ch]:
  //   A = kpk tile (A[row=c<->tok m][k=4g+j<->ch]), B = qpk tile, chained over
  //   the two 16-ch halves. D layout identical to r8's sT -> softmax unchanged.
  u32 Ppk[4][4][2];
#pragma unroll
  for (int nt = 0; nt < 4; ++nt) {
    f32x4 st[4];
#pragma unroll
    for (int mt = 0; mt < 4; ++mt) {
      u32x2 bp = *(const u32x2*)(ws + BIAS_O + (h << 12) + ((16 * nt + c) << 6) + 16 * mt + 4 * g);
      st[mt][0] = bf2f((u16)(bp[0] & 0xffff)); st[mt][1] = bf2f((u16)(bp[0] >> 16));
      st[mt][2] = bf2f((u16)(bp[1] & 0xffff)); st[mt][3] = bf2f((u16)(bp[1] >> 16));
    }
#pragma unroll
    for (int mt = 0; mt < 4; ++mt) {
      st[mt] = __builtin_amdgcn_mfma_f32_16x16x16bf16_1k(
          op16(kpk[0][mt][0], kpk[0][mt][1]), op16(qpk[0][nt][0], qpk[0][nt][1]), st[mt], 0, 0, 0);
      st[mt] = __builtin_amdgcn_mfma_f32_16x16x16bf16_1k(
          op16(kpk[1][mt][0], kpk[1][mt][1]), op16(qpk[1][nt][0], qpk[1][nt][1]), st[mt], 0, 0, 0);
    }
    float mx = st[0][0];
#pragma unroll
    for (int mt = 0; mt < 4; ++mt)
#pragma unroll
      for (int r = 0; r < 4; ++r) mx = fmaxf(mx, st[mt][r]);
    mx = fmaxf(mx, __shfl_xor(mx, 16));
    mx = fmaxf(mx, __shfl_xor(mx, 32));
    float sum = 0.f;
#pragma unroll
    for (int mt = 0; mt < 4; ++mt)
#pragma unroll
      for (int r = 0; r < 4; ++r) { float e = __expf(st[mt][r] - mx); st[mt][r] = e; sum += e; }
    sum += __shfl_xor(sum, 16);
    sum += __shfl_xor(sum, 32);
    float inv = 1.0f / sum;
#pragma unroll
    for (int mt = 0; mt < 4; ++mt) {
      Ppk[mt][nt][0] = pk2(st[mt][0] * inv, st[mt][1] * inv);
      Ppk[mt][nt][1] = pk2(st[mt][2] * inv, st[mt][3] * inv);
    }
  }

  // PV: y^T[d][n] = sum_m v[m][d] P[n][m]: A = vpk tile (v^T frag),
  // B = Ppk tile (P^T frag) -- both direct. D: row=4g+reg<->d, col=c<->n.
  // y written to the SAME [tok][ch] LDS layout as r8 (proj unchanged),
  // now as one 8B packed store per (dt,nt) (4 consecutive channels).
#pragma unroll
  for (int dt = 0; dt < 2; ++dt)
#pragma unroll
    for (int nt = 0; nt < 4; ++nt) {
      f32x4 o2 = {0, 0, 0, 0};
#pragma unroll
      for (int mt = 0; mt < 4; ++mt)
        o2 = __builtin_amdgcn_mfma_f32_16x16x16bf16_1k(
            op16(vpk[dt][mt][0], vpk[dt][mt][1]), op16(Ppk[mt][nt][0], Ppk[mt][nt][1]), o2, 0, 0, 0);
      u32x2 yw;
      yw[0] = pk2(o2[0], o2[1]);
      yw[1] = pk2(o2[2], o2[3]);
      *(u32x2*)(lds + (16 * nt + c) * XROW + (32 * w + 16 * dt + 4 * g) * 2) = yw;
    }
#else
  // ==== fallback: exact r8 attention (frag_from repacks) ====
  bf16x8 bkf[4];
#pragma unroll
  for (int mt = 0; mt < 4; ++mt)
    bkf[mt] = frag_from(kpk[0][mt][0], kpk[0][mt][1], kpk[1][mt][0], kpk[1][mt][1], s0, s1, hi);

  u32 Ppk[4][4][2];
#pragma unroll
  for (int nt = 0; nt < 4; ++nt) {
    bf16x8 aqf = frag_from(qpk[0][nt][0], qpk[0][nt][1], qpk[1][nt][0], qpk[1][nt][1], s0, s1, hi);
    f32x4 st[4];
#pragma unroll
    for (int mt = 0; mt < 4; ++mt) {
      u32x2 bp = *(const u32x2*)(ws + BIAS_O + (h << 12) + ((16 * nt + c) << 6) + 16 * mt + 4 * g);
      st[mt][0] = bf2f((u16)(bp[0] & 0xffff)); st[mt][1] = bf2f((u16)(bp[0] >> 16));
      st[mt][2] = bf2f((u16)(bp[1] & 0xffff)); st[mt][3] = bf2f((u16)(bp[1] >> 16));
    }
#pragma unroll
    for (int mt = 0; mt < 4; ++mt)
      st[mt] = __builtin_amdgcn_mfma_f32_16x16x32_bf16(bkf[mt], aqf, st[mt], 0, 0, 0);
    float mx = st[0][0];
#pragma unroll
    for (int mt = 0; mt < 4; ++mt)
#pragma unroll
      for (int r = 0; r < 4; ++r) mx = fmaxf(mx, st[mt][r]);
    mx = fmaxf(mx, __shfl_xor(mx, 16));
    mx = fmaxf(mx, __shfl_xor(mx, 32));
    float sum = 0.f;
#pragma unroll
    for (int mt = 0; mt < 4; ++mt)
#pragma unroll
      for (int r = 0; r < 4; ++r) { float e = __expf(st[mt][r] - mx); st[mt][r] = e; sum += e; }
    sum += __shfl_xor(sum, 16);
    sum += __shfl_xor(sum, 32);
    float inv = 1.0f / sum;
#pragma unroll
    for (int mt = 0; mt < 4; ++mt) {
      Ppk[mt][nt][0] = pk2(st[mt][0] * inv, st[mt][1] * inv);
      Ppk[mt][nt][1] = pk2(st[mt][2] * inv, st[mt][3] * inv);
    }
  }

  f32x4 o[4][2] = {{{0,0,0,0},{0,0,0,0}},{{0,0,0,0},{0,0,0,0}},
                   {{0,0,0,0},{0,0,0,0}},{{0,0,0,0},{0,0,0,0}}};
#pragma unroll
  for (int k2 = 0; k2 < 2; ++k2) {
    bf16x8 paf4[4];
#pragma unroll
    for (int nt = 0; nt < 4; ++nt)
      paf4[nt] = frag_from(Ppk[2 * k2][nt][0], Ppk[2 * k2][nt][1],
                           Ppk[2 * k2 + 1][nt][0], Ppk[2 * k2 + 1][nt][1], s0, s1, hi);
#pragma unroll
    for (int nt = 0; nt < 4; ++nt) {
      o[nt][0] = __builtin_amdgcn_mfma_f32_16x16x32_bf16(paf4[nt], bvf[0][k2], o[nt][0], 0, 0, 0);
      o[nt][1] = __builtin_amdgcn_mfma_f32_16x16x32_bf16(paf4[nt], bvf[1][k2], o[nt][1], 0, 0, 0);
    }
  }
#pragma unroll
  for (int nt = 0; nt < 4; ++nt)
#pragma unroll
    for (int dt = 0; dt < 2; ++dt)
#pragma unroll
      for (int r = 0; r < 4; ++r) {
        int n = 16 * nt + 4 * g + r, col = 32 * w + 16 * dt + c;
        *(u16*)(lds + n * XROW + col * 2) = f2bf(o[nt][dt][r]);
      }
#endif
  __syncthreads();   // B3: y complete

  // ---- proj: out = y @ w_proj^T + b_proj (r8-verified; y layout unchanged)
  float* gout = out + (size_t)b * (NTOK * CDIM);
#pragma unroll
  for (int ct = 0; ct < 2; ++ct) {
    const int colw = 32 * w + 16 * ct + c;
    const float badd = bf2f(ws[BPRJ_O + colw]);
    f32x4 acc[4];
#pragma unroll
    for (int rt = 0; rt < 4; ++rt)
#pragma unroll
      for (int r = 0; r < 4; ++r) acc[rt][r] = badd;
    const u16* wrow = ws + WPRJ_O + colw * CDIM;
#pragma unroll
    for (int ks = 0; ks < 8; ++ks) {
      bf16x8 wf = *(const bf16x8*)(wrow + ks * 32 + g * 8);
#pragma unroll
      for (int rt = 0; rt < 4; ++rt) {
        bf16x8 ay = *(const bf16x8*)(lds + (16 * rt + c) * XROW + ks * 64 + g * 16);
        acc[rt] = __builtin_amdgcn_mfma_f32_16x16x32_bf16(ay, wf, acc[rt], 0, 0, 0);
      }
    }
#pragma unroll
    for (int rt = 0; rt < 4; ++rt)
#pragma unroll
      for (int r = 0; r < 4; ++r) {
        int n = 16 * rt + 4 * g + r;
        gout[n * CDIM + colw] = acc[rt][r];
      }
  }
}

extern "C" void kernel_launch(void* const* d_in, const int* in_sizes, int n_in,
                              void* d_out, int out_size, void* d_ws, size_t ws_size,
                              hipStream_t stream) {
  (void)in_sizes; (void)n_in; (void)out_size; (void)ws_size;
  detect_dtype<<<dim3(1), dim3(256), 0, stream>>>((const u16*)d_in[0], (int*)d_ws);
  cvt_params<<<dim3(1156), dim3(256), 0, stream>>>(d_in[1], d_in[2], d_in[3], d_in[4],
                                                   d_in[5], d_ws);
  win_attn_fused<<<dim3(4096), dim3(512), 0, stream>>>(d_in[0], d_ws, (float*)d_out);
}